// Round 1
// baseline (458.297 us; speedup 1.0000x reference)
//
#include <hip/hip_runtime.h>

typedef unsigned short u16;
typedef unsigned int u32;
typedef __attribute__((ext_vector_type(8))) short short8;
typedef __attribute__((ext_vector_type(4))) float floatx4;

static constexpr int M = 16384, N = 2048, K = 2048;

// ---- helpers -------------------------------------------------------------

__device__ inline u16 f32_to_bf16(float x) {
    u32 u = __float_as_uint(x);
    u += 0x7FFFu + ((u >> 16) & 1u);
    return (u16)(u >> 16);
}

// RNE round to e4m3 grid; valid for x in [2^-6, 448] (normal e4m3 range,
// guaranteed by the preceding clip). 3 mantissa bits -> round at fp32 bit 20.
__device__ inline float e4m3_rne(float x) {
    u32 u = __float_as_uint(x);
    u += 0x7FFFFu + ((u >> 20) & 1u);
    u &= 0xFFF00000u;
    return __uint_as_float(u);
}

// decode fp4 e2m1 code (4 bits incl. sign) -> float {0,.5,1,1.5,2,3,4,6}*sign
__device__ inline float fp4_dec(u32 c) {
    u32 e = (c >> 1) & 3u;
    float m = (float)(c & 1u);
    float v = e ? (2.0f + m) * (float)(1u << e) * 0.25f : 0.5f * m;
    return (c & 8u) ? -v : v;
}

// reference fp4_121_positive with jnp.round == RNE == rintf
__device__ inline float fp4_round_mag(float a) {
    if (a < 2.0f) return rintf(2.0f * a) * 0.5f;
    if (a < 4.0f) return rintf(a);
    return 2.0f * rintf(a * 0.5f);
}

__device__ inline float pts_from_amax(float amax) {
    // clip(amax / 448, 2^-6, 448); true IEEE division to match reference
    return fminf(fmaxf(amax / 448.0f, 0.015625f), 448.0f);
}

// ---- kernel 1a: per-block partial amax (no atomics) ---------------------

__global__ void amax_part(const float4* __restrict__ x, float* __restrict__ part, int n4) {
    int idx = blockIdx.x * blockDim.x + threadIdx.x;
    int stride = gridDim.x * blockDim.x;
    float m = 0.0f;
    for (int i = idx; i < n4; i += stride) {
        float4 v = x[i];
        m = fmaxf(m, fmaxf(fmaxf(fabsf(v.x), fabsf(v.y)), fmaxf(fabsf(v.z), fabsf(v.w))));
    }
#pragma unroll
    for (int off = 32; off > 0; off >>= 1)
        m = fmaxf(m, __shfl_down(m, off));
    __shared__ float sm[4];
    if ((threadIdx.x & 63) == 0) sm[threadIdx.x >> 6] = m;
    __syncthreads();
    if (threadIdx.x == 0)
        part[blockIdx.x] = fmaxf(fmaxf(sm[0], sm[1]), fmaxf(sm[2], sm[3]));
}

// ---- kernel 1b: finalize amax (1 block, 1024 threads, 2048 partials) ----

__global__ void amax_fin(const float* __restrict__ part, u32* __restrict__ out) {
    int t = threadIdx.x;
    float m = fmaxf(part[t], part[t + 1024]);
#pragma unroll
    for (int off = 32; off > 0; off >>= 1)
        m = fmaxf(m, __shfl_down(m, off));
    __shared__ float sm[16];
    if ((t & 63) == 0) sm[t >> 6] = m;
    __syncthreads();
    if (t < 16) {
        m = sm[t];
#pragma unroll
        for (int off = 8; off > 0; off >>= 1)
            m = fmaxf(m, __shfl_down(m, off));
        if (t == 0) *out = __float_as_uint(m);
    }
}

// ---- kernel 2: fused prep ------------------------------------------------
// blocks [0, QB)          : QDQ x -> bf16 A = lp * sbs (exact in bf16)
// blocks [QB, QB + DB)    : dequant packed weight -> bf16 B = w4 * wsc

static constexpr int QB = (M * K / 4) / 256;        // 32768 quant blocks
static constexpr int DB = (N * (K / 2)) / 256;      // 8192 dequant blocks

__global__ void prep(const float4* __restrict__ x, uint2* __restrict__ aq,
                     const u32* __restrict__ amax_bits,
                     const int* __restrict__ wp, const float* __restrict__ wsc,
                     const float* __restrict__ wgs, u16* __restrict__ wq) {
    if (blockIdx.x < QB) {
        // --- quant path: 4 lanes per 16-block, float4 per lane ---
        int idx = blockIdx.x * blockDim.x + threadIdx.x;
        float4 v = x[idx];

        float bm = fmaxf(fmaxf(fabsf(v.x), fabsf(v.y)), fmaxf(fabsf(v.z), fabsf(v.w)));
        bm = fmaxf(bm, __shfl_xor(bm, 1));
        bm = fmaxf(bm, __shfl_xor(bm, 2));   // 4-lane group = one 16-block

        float pts = pts_from_amax(__uint_as_float(*amax_bits));
        float bs = bm / 6.0f;                                    // block_scale
        float sbs = e4m3_rne(fminf(fmaxf(bs / pts, 0.015625f), 448.0f));
        float ts = pts * sbs;                                    // total_scale

        float vf[4] = {v.x, v.y, v.z, v.w};
        u16 o[4];
#pragma unroll
        for (int i = 0; i < 4; i++) {
            float s = vf[i] / ts;                                // IEEE div, matches ref
            s = fminf(fmaxf(s, -6.0f), 6.0f);
            float lp = copysignf(fp4_round_mag(fabsf(s)), s);
            o[i] = f32_to_bf16(lp * sbs);                        // exact product
        }
        aq[idx] = *(const uint2*)o;
    } else {
        // --- weight dequant path ---
        int idx = (blockIdx.x - QB) * blockDim.x + threadIdx.x;
        constexpr int Khalf = K / 2;                 // 1024
        int n = idx >> 10;
        int kb = idx & (Khalf - 1);
        u32 byte = (u32)wp[idx] & 0xFFu;
        float scale = wsc[(size_t)n * (K / 16) + (kb >> 3)] / wgs[0];
        float lo = fp4_dec(byte & 0xFu) * scale;
        float hi = fp4_dec((byte >> 4) & 0xFu) * scale;
        u32 out = (u32)f32_to_bf16(lo) | ((u32)f32_to_bf16(hi) << 16);
        ((u32*)wq)[idx] = out;                       // wq[n*K + 2*kb .. +1]
    }
}

// ---- kernel 3: bf16 GEMM, C[m,n] = pts * sum_k A[m,k]*B[n,k] ------------
//
// v2: 256x256 tile, 512 threads (8 waves, 2x4), counted-vmcnt deep pipeline
// (T3+T4). LDS is a 4-slot ring of K=32 slabs (A 16KiB + B 16KiB per slot,
// 128 KiB total, 1 block/CU). Steady state keeps 3 slabs (12 loads/thread)
// in flight; each slab boundary is ONE raw s_barrier + s_waitcnt vmcnt(8) --
// never a vmcnt(0) drain until the 2-slab epilogue. This removes the
// per-K-step full drain that capped the previous structure at ~790 TF.
//
// Hazards: RAW -- each wave waits vmcnt(8) (its own slab-t loads landed)
// before the barrier; all waves read after it. WAR -- STAGE(t+3) targets
// slot (t-1)&3, whose last readers finished their (lgkm-complete) ds_reads
// before the iter-t barrier; the stage is issued after that barrier.
// 64-byte LDS rows keep fragment ds_read_b128 bank-uniform (same pattern
// as the previous kernel; no swizzle needed at this row width).

#define GLDS(g, l)                                                              \
    __builtin_amdgcn_global_load_lds(                                           \
        (const __attribute__((address_space(1))) unsigned int*)(g),             \
        (__attribute__((address_space(3))) unsigned int*)(l), 16, 0, 0)

__device__ inline void compute_slab(const u16* __restrict__ sA,
                                    const u16* __restrict__ sB,
                                    floatx4 acc[8][4]) {
    short8 af[8], bf[4];
#pragma unroll
    for (int i = 0; i < 8; i++) af[i] = *(const short8*)(sA + i * 512);
#pragma unroll
    for (int j = 0; j < 4; j++) bf[j] = *(const short8*)(sB + j * 512);
#pragma unroll
    for (int i = 0; i < 8; i++)
#pragma unroll
        for (int j = 0; j < 4; j++)
            acc[i][j] = __builtin_amdgcn_mfma_f32_16x16x32_bf16(
                af[i], bf[j], acc[i][j], 0, 0, 0);
}

__global__ __launch_bounds__(512, 2) void gemm_bt(
    const u16* __restrict__ A, const u16* __restrict__ B,
    float* __restrict__ C, const u32* __restrict__ amax_bits)
{
    // 4-slot ring: slot s holds k-slab [s*32, s*32+32) mod 128 of the k-tile
    __shared__ u16 lA[4][256 * 32];   // [slot][row*32 + k]
    __shared__ u16 lB[4][256 * 32];
    constexpr int SLOT = 256 * 32;    // u16 per slot (16 KiB)

    const int tid = threadIdx.x;
    const int w = tid >> 6, lane = tid & 63;

    // XCD swizzle (512 blocks, 512%8==0 -> bijective): each XCD gets 8
    // consecutive bm rows x all 8 bn -> A tile resident in one L2.
    const int id = blockIdx.x;
    const int xcd = id & 7;
    const int local = id >> 3;                   // 0..63 per XCD
    const int bm = xcd * 8 + (local >> 3);       // 0..63  (M/256)
    const int bn = local & 7;                    // 0..7   (N/256)

    const int wm = w >> 2, wn = w & 3;           // 2x4 wave grid
    const int r16 = lane & 15, q = lane >> 4;

    floatx4 acc[8][4] = {};

    // staging: per slab, wave w + instr e cover rows (w*2+e)*16 .. +16 of
    // A and B (16 rows x 64 B = 1024 B contiguous LDS = one global_load_lds).
    const int srow = lane >> 2;                  // 0..15
    const int sq8 = (lane & 3) * 8;              // 16B k-chunk within 64B row
    const u16* gA0 = A + (size_t)(bm * 256 + (w * 2 + 0) * 16 + srow) * K + sq8;
    const u16* gA1 = A + (size_t)(bm * 256 + (w * 2 + 1) * 16 + srow) * K + sq8;
    const u16* gB0 = B + (size_t)(bn * 256 + (w * 2 + 0) * 16 + srow) * K + sq8;
    const u16* gB1 = B + (size_t)(bn * 256 + (w * 2 + 1) * 16 + srow) * K + sq8;
    u16* dA0 = &lA[0][(w * 2 + 0) * 512];        // wave-uniform LDS bases
    u16* dA1 = &lA[0][(w * 2 + 1) * 512];
    u16* dB0 = &lB[0][(w * 2 + 0) * 512];
    u16* dB1 = &lB[0][(w * 2 + 1) * 512];

#define STAGE(u) do {                                                          \
        const int _s = (u) & 3; const int _kt = (u) * 32;                      \
        GLDS(gA0 + _kt, dA0 + _s * SLOT);                                      \
        GLDS(gA1 + _kt, dA1 + _s * SLOT);                                      \
        GLDS(gB0 + _kt, dB0 + _s * SLOT);                                      \
        GLDS(gB1 + _kt, dB1 + _s * SLOT);                                      \
    } while (0)

    // fragment read bases (lane-fixed)
    const u16* sAb = &lA[0][(wm * 128 + r16) * 32 + q * 8];
    const u16* sBb = &lB[0][(wn * 64 + r16) * 32 + q * 8];

    constexpr int NT = K / 32;                   // 64 slabs

    STAGE(0); STAGE(1); STAGE(2);                // 12 loads in flight

#pragma unroll 1
    for (int t = 0; t < NT - 3; ++t) {
        asm volatile("s_waitcnt vmcnt(8)" ::: "memory");   // slab t landed
        __builtin_amdgcn_s_barrier();
        __builtin_amdgcn_sched_barrier(0);
        STAGE(t + 3);                            // slot (t-1)&3, readers done
        const int s = t & 3;
        compute_slab(sAb + s * SLOT, sBb + s * SLOT, acc);
    }
    // epilogue: drain 8 -> 4 -> 0
    asm volatile("s_waitcnt vmcnt(8)" ::: "memory");
    __builtin_amdgcn_s_barrier();
    __builtin_amdgcn_sched_barrier(0);
    compute_slab(sAb + ((NT - 3) & 3) * SLOT, sBb + ((NT - 3) & 3) * SLOT, acc);
    asm volatile("s_waitcnt vmcnt(4)" ::: "memory");
    __builtin_amdgcn_s_barrier();
    __builtin_amdgcn_sched_barrier(0);
    compute_slab(sAb + ((NT - 2) & 3) * SLOT, sBb + ((NT - 2) & 3) * SLOT, acc);
    asm volatile("s_waitcnt vmcnt(0)" ::: "memory");
    __builtin_amdgcn_s_barrier();
    __builtin_amdgcn_sched_barrier(0);
    compute_slab(sAb + ((NT - 1) & 3) * SLOT, sBb + ((NT - 1) & 3) * SLOT, acc);

    float pts = pts_from_amax(__uint_as_float(*amax_bits));

    // C/D layout (verified m89/m91): col = lane&15, row = (lane>>4)*4 + reg
    float* Cb = C + (size_t)(bm * 256 + wm * 128 + q * 4) * N
                  + bn * 256 + wn * 64 + r16;
#pragma unroll
    for (int i = 0; i < 8; i++)
#pragma unroll
        for (int j = 0; j < 4; j++)
#pragma unroll
            for (int t = 0; t < 4; t++)
                Cb[(size_t)(i * 16 + t) * N + j * 16] = pts * acc[i][j][t];
}

// ---- launch --------------------------------------------------------------

extern "C" void kernel_launch(void* const* d_in, const int* in_sizes, int n_in,
                              void* d_out, int out_size, void* d_ws, size_t ws_size,
                              hipStream_t stream) {
    const float* x   = (const float*)d_in[0];
    const int*   wp  = (const int*)d_in[1];
    const float* wsc = (const float*)d_in[2];
    const float* wgs = (const float*)d_in[3];
    float* out = (float*)d_out;

    // workspace layout:
    //   +0      : amax bits (u32, written by amax_fin)
    //   +64     : 2048 float partial maxima
    //   +16384  : A bf16 [M*K]
    //   then    : B bf16 [N*K]
    u32*   amax_ws = (u32*)d_ws;
    float* part    = (float*)((char*)d_ws + 64);
    u16*   aq      = (u16*)((char*)d_ws + 16384);
    u16*   wq      = aq + (size_t)M * K;

    amax_part<<<2048, 256, 0, stream>>>((const float4*)x, part, M * K / 4);
    amax_fin<<<1, 1024, 0, stream>>>(part, amax_ws);
    prep<<<QB + DB, 256, 0, stream>>>((const float4*)x, (uint2*)aq, amax_ws,
                                      wp, wsc, wgs, wq);
    gemm_bt<<<(M / 256) * (N / 256), 512, 0, stream>>>(aq, wq, out, amax_ws);
}

// Round 2
// 378.717 us; speedup vs baseline: 1.2101x; 1.2101x over previous
//
#include <hip/hip_runtime.h>

typedef unsigned short u16;
typedef unsigned int u32;
typedef __attribute__((ext_vector_type(8))) short short8;
typedef __attribute__((ext_vector_type(4))) float floatx4;

static constexpr int M = 16384, N = 2048, K = 2048;

// ---- helpers -------------------------------------------------------------

__device__ inline u16 f32_to_bf16(float x) {
    u32 u = __float_as_uint(x);
    u += 0x7FFFu + ((u >> 16) & 1u);
    return (u16)(u >> 16);
}

// RNE round to e4m3 grid; valid for x in [2^-6, 448] (normal e4m3 range,
// guaranteed by the preceding clip). 3 mantissa bits -> round at fp32 bit 20.
__device__ inline float e4m3_rne(float x) {
    u32 u = __float_as_uint(x);
    u += 0x7FFFFu + ((u >> 20) & 1u);
    u &= 0xFFF00000u;
    return __uint_as_float(u);
}

// decode fp4 e2m1 code (4 bits incl. sign) -> float {0,.5,1,1.5,2,3,4,6}*sign
__device__ inline float fp4_dec(u32 c) {
    u32 e = (c >> 1) & 3u;
    float m = (float)(c & 1u);
    float v = e ? (2.0f + m) * (float)(1u << e) * 0.25f : 0.5f * m;
    return (c & 8u) ? -v : v;
}

// reference fp4_121_positive with jnp.round == RNE == rintf
__device__ inline float fp4_round_mag(float a) {
    if (a < 2.0f) return rintf(2.0f * a) * 0.5f;
    if (a < 4.0f) return rintf(a);
    return 2.0f * rintf(a * 0.5f);
}

__device__ inline float pts_from_amax(float amax) {
    // clip(amax / 448, 2^-6, 448); true IEEE division to match reference
    return fminf(fmaxf(amax / 448.0f, 0.015625f), 448.0f);
}

// ---- kernel 1a: per-block partial amax (no atomics) ---------------------

__global__ void amax_part(const float4* __restrict__ x, float* __restrict__ part, int n4) {
    int idx = blockIdx.x * blockDim.x + threadIdx.x;
    int stride = gridDim.x * blockDim.x;
    float m = 0.0f;
    for (int i = idx; i < n4; i += stride) {
        float4 v = x[i];
        m = fmaxf(m, fmaxf(fmaxf(fabsf(v.x), fabsf(v.y)), fmaxf(fabsf(v.z), fabsf(v.w))));
    }
#pragma unroll
    for (int off = 32; off > 0; off >>= 1)
        m = fmaxf(m, __shfl_down(m, off));
    __shared__ float sm[4];
    if ((threadIdx.x & 63) == 0) sm[threadIdx.x >> 6] = m;
    __syncthreads();
    if (threadIdx.x == 0)
        part[blockIdx.x] = fmaxf(fmaxf(sm[0], sm[1]), fmaxf(sm[2], sm[3]));
}

// ---- kernel 1b: finalize amax (1 block, 1024 threads, 2048 partials) ----

__global__ void amax_fin(const float* __restrict__ part, u32* __restrict__ out) {
    int t = threadIdx.x;
    float m = fmaxf(part[t], part[t + 1024]);
#pragma unroll
    for (int off = 32; off > 0; off >>= 1)
        m = fmaxf(m, __shfl_down(m, off));
    __shared__ float sm[16];
    if ((t & 63) == 0) sm[t >> 6] = m;
    __syncthreads();
    if (t < 16) {
        m = sm[t];
#pragma unroll
        for (int off = 8; off > 0; off >>= 1)
            m = fmaxf(m, __shfl_down(m, off));
        if (t == 0) *out = __float_as_uint(m);
    }
}

// ---- kernel 2: fused prep ------------------------------------------------

static constexpr int QB = (M * K / 4) / 256;        // 32768 quant blocks
static constexpr int DB = (N * (K / 2)) / 256;      // 8192 dequant blocks

__global__ void prep(const float4* __restrict__ x, uint2* __restrict__ aq,
                     const u32* __restrict__ amax_bits,
                     const int* __restrict__ wp, const float* __restrict__ wsc,
                     const float* __restrict__ wgs, u16* __restrict__ wq) {
    if (blockIdx.x < QB) {
        int idx = blockIdx.x * blockDim.x + threadIdx.x;
        float4 v = x[idx];

        float bm = fmaxf(fmaxf(fabsf(v.x), fabsf(v.y)), fmaxf(fabsf(v.z), fabsf(v.w)));
        bm = fmaxf(bm, __shfl_xor(bm, 1));
        bm = fmaxf(bm, __shfl_xor(bm, 2));   // 4-lane group = one 16-block

        float pts = pts_from_amax(__uint_as_float(*amax_bits));
        float bs = bm / 6.0f;
        float sbs = e4m3_rne(fminf(fmaxf(bs / pts, 0.015625f), 448.0f));
        float ts = pts * sbs;

        float vf[4] = {v.x, v.y, v.z, v.w};
        u16 o[4];
#pragma unroll
        for (int i = 0; i < 4; i++) {
            float s = vf[i] / ts;
            s = fminf(fmaxf(s, -6.0f), 6.0f);
            float lp = copysignf(fp4_round_mag(fabsf(s)), s);
            o[i] = f32_to_bf16(lp * sbs);
        }
        aq[idx] = *(const uint2*)o;
    } else {
        int idx = (blockIdx.x - QB) * blockDim.x + threadIdx.x;
        constexpr int Khalf = K / 2;                 // 1024
        int n = idx >> 10;
        int kb = idx & (Khalf - 1);
        u32 byte = (u32)wp[idx] & 0xFFu;
        float scale = wsc[(size_t)n * (K / 16) + (kb >> 3)] / wgs[0];
        float lo = fp4_dec(byte & 0xFu) * scale;
        float hi = fp4_dec((byte >> 4) & 0xFu) * scale;
        u32 out = (u32)f32_to_bf16(lo) | ((u32)f32_to_bf16(hi) << 16);
        ((u32*)wq)[idx] = out;
    }
}

// ---- kernel 3: bf16 GEMM, 256x256 tile, 8-phase counted-vmcnt schedule --
//
// m201-template port. 512 thr = 8 waves (2M x 4N), per-wave C = 128x64 =
// acc[8][4]. K-loop iter = 2 K-tiles (BK=64 each) in a 2-buffer LDS
// (2 buf x {A,B} x 2 half x 128rows x 64cols bf16 = 128 KiB). Per phase:
// {ds_read subtile; issue 1 half-tile stage (2 glds); barrier; 16 MFMA in
// setprio(1); barrier}. vmcnt(4) ONLY at phases 4 & 8.
//
// Per-wave quadrant order (Qa,Qb) = (0,0),(0,1),(1,1),(1,0): B frags for
// all 4 j live across the tile (32 VGPR), A quarter reloaded (32 VGPR).
//
// Stage slot schedule (iter t; X=buf0 holds kt=2t, Y=buf1 holds kt=2t+1):
//   P1: Y.A0<-kt2t+1   (slot freed after P7 of t-1)
//   P2: Y.A1<-kt2t+1
//   P3: X.B0<-kt2t+2   (X.B fully read after P2)
//   P4: X.B1           + vmcnt(4): Y fully landed before P5 reads
//   P5: X.A0<-kt2t+2   (X.A fully read after P3)
//   P6: X.A1
//   P7: Y.B0<-kt2t+3   (Y.B fully read after P6)
//   P8: Y.B1           + vmcnt(4): X' fully landed before next P1
// At each checkpoint 12 loads outstanding, vmcnt(4) leaves the 2 newest
// half-tiles in flight -- never a full drain in the loop.
//
// Bank swizzle (T2, both-sides-or-neither): rows are 128 B; logical column
// byte cb -> physical cb ^ ((row&7)<<4). global_load_lds dest stays linear;
// the SOURCE column is pre-swizzled per lane (same involution), ds_read
// applies the XOR. Post-swizzle each 8-lane group of a b128 read covers
// all 32 banks exactly once.

#define GLDS(g, l)                                                              \
    __builtin_amdgcn_global_load_lds(                                           \
        (const __attribute__((address_space(1))) unsigned int*)(g),             \
        (__attribute__((address_space(3))) unsigned int*)(l), 16, 0, 0)

__global__ __launch_bounds__(512, 2) void gemm_bt(
    const u16* __restrict__ A, const u16* __restrict__ B,
    float* __restrict__ C, const u32* __restrict__ amax_bits)
{
    // [buf][mat A=0/B=1][half][128 rows * 64 cols] bf16, 16 KiB per half
    __shared__ u16 sh[2][2][2][8192];

    const int tid = threadIdx.x;
    const int w = tid >> 6, lane = tid & 63;

    // XCD swizzle (512 blocks, 512%8==0 -> bijective)
    const int id = blockIdx.x;
    const int xcd = id & 7;
    const int local = id >> 3;                   // 0..63 per XCD
    const int bm = xcd * 8 + (local >> 3);       // 0..63  (M/256)
    const int bn = local & 7;                    // 0..7   (N/256)

    const int wm = w >> 2, wn = w & 3;           // 2x4 wave grid
    const int r16 = lane & 15, q = lane >> 4;

    floatx4 acc[8][4] = {};

    // ---- swizzled fragment read offsets (u16 units) ----
    const int swz = (r16 & 7) << 4;                          // byte XOR value
    const int aoff0 = r16 * 64 + (((q * 16) ^ swz) >> 1);          // ks=0
    const int aoff1 = r16 * 64 + (((64 + q * 16) ^ swz) >> 1);     // ks=1

    // ---- staging source pointers (pre-swizzled per lane) ----
    const int srow8 = lane >> 3;                             // 0..7
    const int scol = ((lane & 7) ^ srow8) * 8;               // u16 units
    const u16* gA[2], * gB[2];
    gA[0] = A + (size_t)(bm * 256 + (w * 2 + 0) * 8 + srow8) * K + scol;
    gA[1] = A + (size_t)(bm * 256 + (w * 2 + 1) * 8 + srow8) * K + scol;
    gB[0] = B + (size_t)(bn * 256 + (w * 2 + 0) * 8 + srow8) * K + scol;
    gB[1] = B + (size_t)(bn * 256 + (w * 2 + 1) * 8 + srow8) * K + scol;

#define STG(buf, mat, half, ktc) do {                                           \
        const u16* _s0 = ((mat) ? gB[0] : gA[0]) + (size_t)(half) * 128 * K + (ktc); \
        const u16* _s1 = ((mat) ? gB[1] : gA[1]) + (size_t)(half) * 128 * K + (ktc); \
        GLDS(_s0, &sh[buf][mat][half][w * 1024]);                               \
        GLDS(_s1, &sh[buf][mat][half][w * 1024 + 512]);                         \
    } while (0)

    short8 aF[4][2], bF[4][2];

#define RD_A(buf, Qa) do {                                                      \
        const u16* _ar = &sh[buf][0][wm][(Qa) * 4096];                          \
        _Pragma("unroll") for (int _i = 0; _i < 4; _i++) {                      \
            aF[_i][0] = *(const short8*)(_ar + _i * 1024 + aoff0);              \
            aF[_i][1] = *(const short8*)(_ar + _i * 1024 + aoff1); }            \
    } while (0)

#define RD_B(buf, Qb) do {                                                      \
        const u16* _br = &sh[buf][1][wn >> 1][(wn & 1) * 4096 + (Qb) * 2048];   \
        _Pragma("unroll") for (int _j = 0; _j < 2; _j++) {                      \
            bF[(Qb) * 2 + _j][0] = *(const short8*)(_br + _j * 1024 + aoff0);   \
            bF[(Qb) * 2 + _j][1] = *(const short8*)(_br + _j * 1024 + aoff1); } \
    } while (0)

#define MMA(Qa, Qb) do {                                                        \
        __builtin_amdgcn_sched_barrier(0);                                      \
        __builtin_amdgcn_s_barrier();                                           \
        __builtin_amdgcn_sched_barrier(0);                                      \
        __builtin_amdgcn_s_setprio(1);                                          \
        _Pragma("unroll") for (int _i = 0; _i < 4; _i++)                        \
        _Pragma("unroll") for (int _j = 0; _j < 2; _j++)                        \
        _Pragma("unroll") for (int _k = 0; _k < 2; _k++)                        \
            acc[(Qa) * 4 + _i][(Qb) * 2 + _j] =                                 \
                __builtin_amdgcn_mfma_f32_16x16x32_bf16(                        \
                    aF[_i][_k], bF[(Qb) * 2 + _j][_k],                          \
                    acc[(Qa) * 4 + _i][(Qb) * 2 + _j], 0, 0, 0);                \
        __builtin_amdgcn_s_setprio(0);                                          \
        __builtin_amdgcn_sched_barrier(0);                                      \
    } while (0)

#define ENDPH __builtin_amdgcn_s_barrier()
#define CHK4 do { asm volatile("s_waitcnt vmcnt(4)" ::: "memory");              \
                  __builtin_amdgcn_sched_barrier(0); } while (0)

    // ---- prologue: X(kt0) fully + Y(kt1) B halves; Y.A staged at P1/P2 ----
    STG(0, 0, 0, 0); STG(0, 0, 1, 0);        // X.A0 X.A1
    STG(0, 1, 0, 0); STG(0, 1, 1, 0);        // X.B0 X.B1
    STG(1, 1, 0, 64); STG(1, 1, 1, 64);      // Y.B0 Y.B1
    CHK4;                                     // X landed; Y.B may fly
    __builtin_amdgcn_s_barrier();

#pragma unroll 1
    for (int it = 0; it < K / 128; ++it) {
        const int ktY  = (2 * it + 1) * 64;
        const int kx2  = 2 * it + 2, ky2 = 2 * it + 3;
        const int ktX2 = (kx2 <= 31 ? kx2 : 31) * 64;   // clamp: last-iter
        const int ktY2 = (ky2 <= 31 ? ky2 : 31) * 64;   // stages are dummies

        // ---- X tile (buf 0) ----
        RD_A(0, 0); RD_B(0, 0); STG(1, 0, 0, ktY);  MMA(0, 0);       ENDPH; // P1
        RD_B(0, 1);             STG(1, 0, 1, ktY);  MMA(0, 1);       ENDPH; // P2
        RD_A(0, 1);             STG(0, 1, 0, ktX2); MMA(1, 1);       ENDPH; // P3
                                STG(0, 1, 1, ktX2); MMA(1, 0); CHK4; ENDPH; // P4
        // ---- Y tile (buf 1) ----
        RD_A(1, 0); RD_B(1, 0); STG(0, 0, 0, ktX2); MMA(0, 0);       ENDPH; // P5
        RD_B(1, 1);             STG(0, 0, 1, ktX2); MMA(0, 1);       ENDPH; // P6
        RD_A(1, 1);             STG(1, 1, 0, ktY2); MMA(1, 1);       ENDPH; // P7
                                STG(1, 1, 1, ktY2); MMA(1, 0); CHK4; ENDPH; // P8
    }

    // drain stray (clamped) stages before LDS dealloc / epilogue
    asm volatile("s_waitcnt vmcnt(0)" ::: "memory");

    float pts = pts_from_amax(__uint_as_float(*amax_bits));

    // C/D layout (verified m89/m91): col = lane&15, row = (lane>>4)*4 + reg
    float* Cb = C + (size_t)(bm * 256 + wm * 128 + q * 4) * N
                  + bn * 256 + wn * 64 + r16;
#pragma unroll
    for (int i = 0; i < 8; i++)
#pragma unroll
        for (int j = 0; j < 4; j++)
#pragma unroll
            for (int t = 0; t < 4; t++)
                Cb[(size_t)(i * 16 + t) * N + j * 16] = pts * acc[i][j][t];
}

// ---- launch --------------------------------------------------------------

extern "C" void kernel_launch(void* const* d_in, const int* in_sizes, int n_in,
                              void* d_out, int out_size, void* d_ws, size_t ws_size,
                              hipStream_t stream) {
    const float* x   = (const float*)d_in[0];
    const int*   wp  = (const int*)d_in[1];
    const float* wsc = (const float*)d_in[2];
    const float* wgs = (const float*)d_in[3];
    float* out = (float*)d_out;

    u32*   amax_ws = (u32*)d_ws;
    float* part    = (float*)((char*)d_ws + 64);
    u16*   aq      = (u16*)((char*)d_ws + 16384);
    u16*   wq      = aq + (size_t)M * K;

    amax_part<<<2048, 256, 0, stream>>>((const float4*)x, part, M * K / 4);
    amax_fin<<<1, 1024, 0, stream>>>(part, amax_ws);
    prep<<<QB + DB, 256, 0, stream>>>((const float4*)x, (uint2*)aq, amax_ws,
                                      wp, wsc, wgs, wq);
    gemm_bt<<<(M / 256) * (N / 256), 512, 0, stream>>>(aq, wq, out, amax_ws);
}